// Round 1
// 199.217 us; speedup vs baseline: 1.0097x; 1.0097x over previous
//
#include <hip/hip_runtime.h>
#include <hip/hip_bf16.h>
#include <math.h>

#define N_NODES 50000
#define N_EDGES 800000
#define D0 64
#define D1 128
#define D2 40

#define NB  256   // buckets
#define NPB 196   // nodes per bucket (256*196 = 50176 >= 50000)

typedef short s16x8 __attribute__((ext_vector_type(8)));
typedef float f32x4 __attribute__((ext_vector_type(4)));

static __device__ __forceinline__ unsigned short f2bf(float v) {
    __hip_bfloat16 hb = __float2bfloat16(v);
    return *(unsigned short*)&hb;
}

// ---------------- fused prep: bucket histogram + cast x + pack weights ----------------
__global__ __launch_bounds__(256) void prep_kernel(
        const float* __restrict__ x, const int* __restrict__ dst,
        const float* __restrict__ W1l, const float* __restrict__ W1r,
        const float* __restrict__ W2l, const float* __restrict__ W2r,
        unsigned short* __restrict__ xh, int* __restrict__ hist,
        unsigned short* __restrict__ wpk1, unsigned short* __restrict__ wpk2,
        int E, int nCount, int nCast) {
    int b = blockIdx.x, t = threadIdx.x;
    if (b < nCount) {
        __shared__ int h[NB];
        h[t] = 0;
        __syncthreads();
        int e0 = b * 2048;
        for (int i = t; i < 2048; i += 256) {
            int e = e0 + i;
            if (e < E) atomicAdd(&h[(unsigned)dst[e] / NPB], 1);
        }
        __syncthreads();
        hist[b * NB + t] = h[t];
    } else if (b < nCount + nCast) {
        int i = ((b - nCount) * 256 + t) * 4;   // nCast*1024 == N*D0 exactly
        float4 v = *(const float4*)(x + i);
        unsigned o0 = (unsigned)f2bf(v.x) | ((unsigned)f2bf(v.y) << 16);
        unsigned o1 = (unsigned)f2bf(v.z) | ((unsigned)f2bf(v.w) << 16);
        uint2 pk; pk.x = o0; pk.y = o1;
        *(uint2*)(xh + i) = pk;
    } else if (b < nCount + nCast + 8) {
        int f = (b - nCount - nCast) * 4 + (t >> 6);   // 0..31
        int lane = t & 63;
        int nt = f & 7;
        int col = nt * 16 + (lane & 15);
        int kbase = (f >> 3) * 32 + (lane >> 4) * 8;
        unsigned short* o = wpk1 + ((size_t)f * 64 + lane) * 8;
#pragma unroll
        for (int j = 0; j < 8; ++j) {
            int k = kbase + j;
            float w = (k < 64) ? W1r[k * 128 + col] : W1l[(k - 64) * 128 + col];
            o[j] = f2bf(w);
        }
    } else {
        int f = (b - nCount - nCast - 8) * 4 + (t >> 6);   // 0..19
        if (f < 20) {
            int lane = t & 63;
            int nt = f % 5;
            int col = nt * 16 + (lane & 15);       // 0..79
            int kbase = (f / 5) * 32 + (lane >> 4) * 8;
            unsigned short* o = wpk2 + ((size_t)f * 64 + lane) * 8;
#pragma unroll
            for (int j = 0; j < 8; ++j) {
                int k = kbase + j;
                float w = (col < 40) ? W2l[k * 40 + col] : W2r[k * 40 + (col - 40)];
                o[j] = f2bf(w);
            }
        }
    }
}

// ---------------- scan: column-sum hist + exclusive scan -> bbase/bcursor ----------------
__global__ void bucket_scan_kernel(const int* __restrict__ hist, int nCount,
                                   int* __restrict__ bbase, int* __restrict__ bcursor) {
    __shared__ int sd[NB];
    int t = threadIdx.x;
    int v = 0;
#pragma unroll 4
    for (int b = 0; b < nCount; ++b) v += hist[b * NB + t];
    sd[t] = v;
    __syncthreads();
    for (int off = 1; off < NB; off <<= 1) {
        int u = (t >= off) ? sd[t - off] : 0;
        __syncthreads();
        sd[t] += u;
        __syncthreads();
    }
    int ex = sd[t] - v;
    bbase[t] = ex;
    bcursor[t] = ex;
}

__global__ __launch_bounds__(256) void bucket_scatter_kernel(
        const int* __restrict__ src, const int* __restrict__ dst,
        int* __restrict__ bcursor, unsigned* __restrict__ ebuf, int E) {
    __shared__ int h[NB];
    __shared__ int base[NB];
    int t = threadIdx.x;
    int e0 = blockIdx.x * 4096;
    h[t] = 0;
    __syncthreads();
    for (int i = t; i < 4096; i += 256) {
        int e = e0 + i;
        if (e < E) atomicAdd(&h[(unsigned)dst[e] / NPB], 1);
    }
    __syncthreads();
    if (h[t] > 0) base[t] = atomicAdd(&bcursor[t], h[t]);
    h[t] = 0;
    __syncthreads();
    for (int i = t; i < 4096; i += 256) {
        int e = e0 + i;
        if (e < E) {
            unsigned d = (unsigned)dst[e];
            unsigned b = d / NPB;
            unsigned ld = d - b * NPB;
            int k = atomicAdd(&h[b], 1);
            ebuf[base[b] + k] = (ld << 17) | (unsigned)src[e];
        }
    }
}

__global__ __launch_bounds__(256) void bucket_fill_kernel(
        const unsigned* __restrict__ ebuf, const int* __restrict__ bbase,
        int* __restrict__ rowptr, int* __restrict__ csr, int E, int N) {
    __shared__ int cnt[256];
    __shared__ int sd[256];
    int b = blockIdx.x, t = threadIdx.x;
    int s0 = bbase[b];
    int s1 = (b < NB - 1) ? bbase[b + 1] : E;
    int lo = b * NPB;
    cnt[t] = 0;
    __syncthreads();
    for (int i = s0 + t; i < s1; i += 256)
        atomicAdd(&cnt[ebuf[i] >> 17], 1);
    __syncthreads();
    int v = cnt[t];
    sd[t] = v;
    __syncthreads();
    for (int off = 1; off < 256; off <<= 1) {
        int u = (t >= off) ? sd[t - off] : 0;
        __syncthreads();
        sd[t] += u;
        __syncthreads();
    }
    int ex = sd[t] - v;
    int node = lo + t;
    if (t < NPB && node < N) rowptr[node] = s0 + ex;
    cnt[t] = s0 + ex;
    __syncthreads();
    for (int i = s0 + t; i < s1; i += 256) {
        unsigned pk = ebuf[i];
        int p = atomicAdd(&cnt[pk >> 17], 1);
        csr[p] = (int)(pk & 0x1FFFFu);
    }
    if (b == NB - 1 && t == 0) rowptr[N] = E;
}

// ---------------- agg1: 8 lanes/edge, 8 edges/load-instr, 8-slot padding ----------------

__global__ void agg1_kernel(const unsigned short* __restrict__ xh, const int* __restrict__ rowptr,
                            const int* __restrict__ csr, unsigned short* __restrict__ aggh, int N) {
    int wid = (blockIdx.x * blockDim.x + threadIdx.x) >> 6;
    int lane = threadIdx.x & 63;
    if (wid >= N) return;
    int beg = rowptr[wid], end = rowptr[wid + 1];
    int deg = end - beg;
    int l = lane & 7, g = lane >> 3;
    float acc[8];
#pragma unroll
    for (int k = 0; k < 8; ++k) acc[k] = 0.f;
    int jmax = (deg + 7) >> 3;          // # of 8-slot blocks
    int full = jmax - 1;                // blocks [0,full) are provably full: no clamp, no mask
    int j = 0;
    for (; j + 2 <= full; j += 2) {
        int s0 = csr[beg + j * 8 + g];
        int s1 = csr[beg + (j + 1) * 8 + g];
        uint4 v0 = *(const uint4*)(xh + (size_t)s0 * D0 + l * 8);
        uint4 v1 = *(const uint4*)(xh + (size_t)s1 * D0 + l * 8);
        acc[0] += __uint_as_float(v0.x << 16);          acc[1] += __uint_as_float(v0.x & 0xffff0000u);
        acc[2] += __uint_as_float(v0.y << 16);          acc[3] += __uint_as_float(v0.y & 0xffff0000u);
        acc[4] += __uint_as_float(v0.z << 16);          acc[5] += __uint_as_float(v0.z & 0xffff0000u);
        acc[6] += __uint_as_float(v0.w << 16);          acc[7] += __uint_as_float(v0.w & 0xffff0000u);
        acc[0] += __uint_as_float(v1.x << 16);          acc[1] += __uint_as_float(v1.x & 0xffff0000u);
        acc[2] += __uint_as_float(v1.y << 16);          acc[3] += __uint_as_float(v1.y & 0xffff0000u);
        acc[4] += __uint_as_float(v1.z << 16);          acc[5] += __uint_as_float(v1.z & 0xffff0000u);
        acc[6] += __uint_as_float(v1.w << 16);          acc[7] += __uint_as_float(v1.w & 0xffff0000u);
    }
    if (j < full) {
        int s0 = csr[beg + j * 8 + g];
        uint4 v0 = *(const uint4*)(xh + (size_t)s0 * D0 + l * 8);
        acc[0] += __uint_as_float(v0.x << 16);          acc[1] += __uint_as_float(v0.x & 0xffff0000u);
        acc[2] += __uint_as_float(v0.y << 16);          acc[3] += __uint_as_float(v0.y & 0xffff0000u);
        acc[4] += __uint_as_float(v0.z << 16);          acc[5] += __uint_as_float(v0.z & 0xffff0000u);
        acc[6] += __uint_as_float(v0.w << 16);          acc[7] += __uint_as_float(v0.w & 0xffff0000u);
    }
    if (jmax > 0) {                     // last (possibly partial) block, masked
        int slot = full * 8 + g;
        int e = beg + slot;
        e = (e < end) ? e : (end - 1);
        int s0 = csr[e];
        float w = (slot < deg) ? 1.f : 0.f;
        uint4 v0 = *(const uint4*)(xh + (size_t)s0 * D0 + l * 8);
        acc[0] = fmaf(w, __uint_as_float(v0.x << 16), acc[0]);
        acc[1] = fmaf(w, __uint_as_float(v0.x & 0xffff0000u), acc[1]);
        acc[2] = fmaf(w, __uint_as_float(v0.y << 16), acc[2]);
        acc[3] = fmaf(w, __uint_as_float(v0.y & 0xffff0000u), acc[3]);
        acc[4] = fmaf(w, __uint_as_float(v0.z << 16), acc[4]);
        acc[5] = fmaf(w, __uint_as_float(v0.z & 0xffff0000u), acc[5]);
        acc[6] = fmaf(w, __uint_as_float(v0.w << 16), acc[6]);
        acc[7] = fmaf(w, __uint_as_float(v0.w & 0xffff0000u), acc[7]);
    }
#pragma unroll
    for (int off = 8; off <= 32; off <<= 1) {
#pragma unroll
        for (int k = 0; k < 8; ++k) acc[k] += __shfl_xor(acc[k], off);
    }
    float inv = 1.f / (float)max(deg, 1);
    if (g == 0) {
        unsigned o0 = (unsigned)f2bf(acc[0] * inv) | ((unsigned)f2bf(acc[1] * inv) << 16);
        unsigned o1 = (unsigned)f2bf(acc[2] * inv) | ((unsigned)f2bf(acc[3] * inv) << 16);
        unsigned o2 = (unsigned)f2bf(acc[4] * inv) | ((unsigned)f2bf(acc[5] * inv) << 16);
        unsigned o3 = (unsigned)f2bf(acc[6] * inv) | ((unsigned)f2bf(acc[7] * inv) << 16);
        uint4 pk; pk.x = o0; pk.y = o1; pk.z = o2; pk.w = o3;
        *(uint4*)(aggh + (size_t)wid * D0 + l * 8) = pk;
    }
}

// ---------------- agg2 + log_softmax: 5 lanes/edge x uint4, 12 edges/instr ----------------
// p2h rows padded to 64 shorts (128 B) -> every edge gather = exactly one cache line

__global__ void agg2_kernel(const unsigned short* __restrict__ p2h, const float* __restrict__ r2,
                            const int* __restrict__ rowptr, const int* __restrict__ csr,
                            float* __restrict__ out, float* __restrict__ out2, int N) {
    int wid = (blockIdx.x * blockDim.x + threadIdx.x) >> 6;
    int lane = threadIdx.x & 63;
    if (wid >= N) return;
    int beg = rowptr[wid], end = rowptr[wid + 1];
    int deg = end - beg;
    int g = lane / 5;             // 0..12 (g==12: lanes 60..63 idle)
    int l = lane - g * 5;         // 0..4
    bool gv = g < 12;
    float a[8];
#pragma unroll
    for (int k = 0; k < 8; ++k) a[k] = 0.f;
    int jmax = (deg + 11) / 12;   // # of 12-slot blocks
    int full = jmax - 1;          // blocks [0,full): every slot < deg, addr < end even for g==12
    int j = 0;
    for (; j + 2 <= full; j += 2) {
        int s0 = csr[beg + j * 12 + g];
        int s1 = csr[beg + (j + 1) * 12 + g];
        uint4 v0 = *(const uint4*)(p2h + (size_t)s0 * 64 + l * 8);
        uint4 v1 = *(const uint4*)(p2h + (size_t)s1 * 64 + l * 8);
        if (gv) {
            a[0] += __uint_as_float(v0.x << 16);  a[1] += __uint_as_float(v0.x & 0xffff0000u);
            a[2] += __uint_as_float(v0.y << 16);  a[3] += __uint_as_float(v0.y & 0xffff0000u);
            a[4] += __uint_as_float(v0.z << 16);  a[5] += __uint_as_float(v0.z & 0xffff0000u);
            a[6] += __uint_as_float(v0.w << 16);  a[7] += __uint_as_float(v0.w & 0xffff0000u);
            a[0] += __uint_as_float(v1.x << 16);  a[1] += __uint_as_float(v1.x & 0xffff0000u);
            a[2] += __uint_as_float(v1.y << 16);  a[3] += __uint_as_float(v1.y & 0xffff0000u);
            a[4] += __uint_as_float(v1.z << 16);  a[5] += __uint_as_float(v1.z & 0xffff0000u);
            a[6] += __uint_as_float(v1.w << 16);  a[7] += __uint_as_float(v1.w & 0xffff0000u);
        }
    }
    if (j < full) {
        int s0 = csr[beg + j * 12 + g];
        uint4 v0 = *(const uint4*)(p2h + (size_t)s0 * 64 + l * 8);
        if (gv) {
            a[0] += __uint_as_float(v0.x << 16);  a[1] += __uint_as_float(v0.x & 0xffff0000u);
            a[2] += __uint_as_float(v0.y << 16);  a[3] += __uint_as_float(v0.y & 0xffff0000u);
            a[4] += __uint_as_float(v0.z << 16);  a[5] += __uint_as_float(v0.z & 0xffff0000u);
            a[6] += __uint_as_float(v0.w << 16);  a[7] += __uint_as_float(v0.w & 0xffff0000u);
        }
    }
    if (jmax > 0) {               // last block, masked + clamped
        int slot = full * 12 + g;
        int e = beg + slot;
        e = (e < end) ? e : (end - 1);
        int s0 = csr[e];
        float w = (gv && slot < deg) ? 1.f : 0.f;
        uint4 v0 = *(const uint4*)(p2h + (size_t)s0 * 64 + l * 8);
        a[0] = fmaf(w, __uint_as_float(v0.x << 16), a[0]);
        a[1] = fmaf(w, __uint_as_float(v0.x & 0xffff0000u), a[1]);
        a[2] = fmaf(w, __uint_as_float(v0.y << 16), a[2]);
        a[3] = fmaf(w, __uint_as_float(v0.y & 0xffff0000u), a[3]);
        a[4] = fmaf(w, __uint_as_float(v0.z << 16), a[4]);
        a[5] = fmaf(w, __uint_as_float(v0.z & 0xffff0000u), a[5]);
        a[6] = fmaf(w, __uint_as_float(v0.w << 16), a[6]);
        a[7] = fmaf(w, __uint_as_float(v0.w & 0xffff0000u), a[7]);
    }
    // reduce 12 groups -> group 0 (lanes 0..4, 8 dims each)
    {
        float b0;
#pragma unroll
        for (int k = 0; k < 8; ++k) { b0 = __shfl(a[k], lane + 30); if (g < 6) a[k] += b0; }
#pragma unroll
        for (int k = 0; k < 8; ++k) { b0 = __shfl(a[k], lane + 15); if (g < 3) a[k] += b0; }
#pragma unroll
        for (int k = 0; k < 8; ++k) {
            float b1 = __shfl(a[k], lane + 5);
            float b2 = __shfl(a[k], lane + 10);
            if (g == 0) a[k] += b1 + b2;
        }
    }
    float inv = 1.f / (float)max(deg, 1);
    bool wr = (lane < 5);
    float h2[8];
    if (wr) {
        float4 ra = *(const float4*)(r2 + (size_t)wid * D2 + lane * 8);
        float4 rb = *(const float4*)(r2 + (size_t)wid * D2 + lane * 8 + 4);
        h2[0] = ra.x + a[0] * inv; h2[1] = ra.y + a[1] * inv;
        h2[2] = ra.z + a[2] * inv; h2[3] = ra.w + a[3] * inv;
        h2[4] = rb.x + a[4] * inv; h2[5] = rb.y + a[5] * inv;
        h2[6] = rb.z + a[6] * inv; h2[7] = rb.w + a[7] * inv;
        float4 oa; oa.x = h2[0]; oa.y = h2[1]; oa.z = h2[2]; oa.w = h2[3];
        float4 ob; ob.x = h2[4]; ob.y = h2[5]; ob.z = h2[6]; ob.w = h2[7];
        *(float4*)(out + (size_t)wid * D2 + lane * 8) = oa;
        *(float4*)(out + (size_t)wid * D2 + lane * 8 + 4) = ob;
    }
    float m = -INFINITY;
    if (wr) {
#pragma unroll
        for (int k = 0; k < 8; ++k) m = fmaxf(m, h2[k]);
    }
#pragma unroll
    for (int off = 1; off < 64; off <<= 1) m = fmaxf(m, __shfl_xor(m, off));
    float s = 0.f;
    if (wr) {
#pragma unroll
        for (int k = 0; k < 8; ++k) s += expf(h2[k] - m);
    }
#pragma unroll
    for (int off = 1; off < 64; off <<= 1) s += __shfl_xor(s, off);
    if (wr) {
        float lg = m + logf(s);
        float4 oa; oa.x = h2[0] - lg; oa.y = h2[1] - lg; oa.z = h2[2] - lg; oa.w = h2[3] - lg;
        float4 ob; ob.x = h2[4] - lg; ob.y = h2[5] - lg; ob.z = h2[6] - lg; ob.w = h2[7] - lg;
        *(float4*)(out2 + (size_t)wid * D2 + lane * 8) = oa;
        *(float4*)(out2 + (size_t)wid * D2 + lane * 8 + 4) = ob;
    }
}

// ---------------- fused GEMM: h=relu([x|agg]@[W1r;W1l]+b1) staged in LDS, then
//                  p2h(bf16,stride64)=h@W2l ; r2(f32)=h@W2r+b2 ----------------
__global__ __launch_bounds__(256) void gemm_fused(
        const unsigned short* __restrict__ xh, const unsigned short* __restrict__ aggh,
        const unsigned short* __restrict__ Wpk1, const unsigned short* __restrict__ Wpk2,
        const float* __restrict__ b1, const float* __restrict__ b2,
        unsigned short* __restrict__ p2h, float* __restrict__ r2, int N) {
    __shared__ __align__(16) unsigned short As[128 * 136];  // [row][k], +8 pad
    int t = threadIdx.x;
    int r0 = blockIdx.x * 128;
    for (int i = t; i < 2048; i += 256) {
        int r = i >> 4, c = i & 15;
        int gr = r0 + r; gr = (gr < N) ? gr : (N - 1);
        uint4 v = (c < 8) ? ((const uint4*)(xh + (size_t)gr * 64))[c]
                          : ((const uint4*)(aggh + (size_t)gr * 64))[c - 8];
        *(uint4*)(As + r * 136 + c * 8) = v;
    }
    __syncthreads();
    int w = t >> 6, lane = t & 63;
    int l15 = lane & 15, q = lane >> 4;
    f32x4 zero = {0.f, 0.f, 0.f, 0.f};
    const unsigned short* abase = As + (w * 32 + l15) * 136 + q * 8;

    // ---- phase 1: [x|agg] @ [W1r;W1l] ----
    f32x4 acc[2][8];
#pragma unroll
    for (int rt = 0; rt < 2; ++rt)
#pragma unroll
        for (int nt = 0; nt < 8; ++nt) acc[rt][nt] = zero;
#pragma unroll
    for (int ks = 0; ks < 4; ++ks) {
        s16x8 a0 = *(const s16x8*)(abase + ks * 32);
        s16x8 a1 = *(const s16x8*)(abase + 16 * 136 + ks * 32);
        s16x8 b[8];
#pragma unroll
        for (int nt = 0; nt < 8; ++nt)
            b[nt] = *(const s16x8*)(Wpk1 + ((size_t)(ks * 8 + nt) * 64 + lane) * 8);
#pragma unroll
        for (int nt = 0; nt < 8; ++nt) {
            acc[0][nt] = __builtin_amdgcn_mfma_f32_16x16x32_bf16(a0, b[nt], acc[0][nt], 0, 0, 0);
            acc[1][nt] = __builtin_amdgcn_mfma_f32_16x16x32_bf16(a1, b[nt], acc[1][nt], 0, 0, 0);
        }
    }
    __syncthreads();   // all reads of As complete before overwrite
    // ---- stage h = relu(acc + b1) back into As (each wave owns rows [w*32, w*32+32)) ----
    int rloc = w * 32 + q * 4;
#pragma unroll
    for (int nt = 0; nt < 8; ++nt) {
        int col = nt * 16 + l15;
        float bias = b1[col];
#pragma unroll
        for (int rt = 0; rt < 2; ++rt) {
#pragma unroll
            for (int reg = 0; reg < 4; ++reg) {
                int row = rloc + rt * 16 + reg;
                As[row * 136 + col] = f2bf(fmaxf(acc[rt][nt][reg] + bias, 0.f));
            }
        }
    }
    __syncthreads();
    // ---- phase 2: h @ [W2l|W2r] ----
    f32x4 acc2[2][5];
#pragma unroll
    for (int rt = 0; rt < 2; ++rt)
#pragma unroll
        for (int nt = 0; nt < 5; ++nt) acc2[rt][nt] = zero;
#pragma unroll
    for (int ks = 0; ks < 4; ++ks) {
        s16x8 a0 = *(const s16x8*)(abase + ks * 32);
        s16x8 a1 = *(const s16x8*)(abase + 16 * 136 + ks * 32);
        s16x8 b[5];
#pragma unroll
        for (int nt = 0; nt < 5; ++nt)
            b[nt] = *(const s16x8*)(Wpk2 + ((size_t)(ks * 5 + nt) * 64 + lane) * 8);
#pragma unroll
        for (int nt = 0; nt < 5; ++nt) {
            acc2[0][nt] = __builtin_amdgcn_mfma_f32_16x16x32_bf16(a0, b[nt], acc2[0][nt], 0, 0, 0);
            acc2[1][nt] = __builtin_amdgcn_mfma_f32_16x16x32_bf16(a1, b[nt], acc2[1][nt], 0, 0, 0);
        }
    }
    int rbase = r0 + w * 32 + q * 4;
#pragma unroll
    for (int nt = 0; nt < 5; ++nt) {
        int col = nt * 16 + l15;   // 0..79
        bool isp = col < 40;
        int oc = isp ? col : (col - 40);
        float bias = isp ? 0.f : b2[oc];
#pragma unroll
        for (int rt = 0; rt < 2; ++rt) {
#pragma unroll
            for (int reg = 0; reg < 4; ++reg) {
                int row = rbase + rt * 16 + reg;
                if (row < N) {
                    float v = acc2[rt][nt][reg] + bias;
                    if (isp) p2h[(size_t)row * 64 + oc] = f2bf(v);
                    else     r2[(size_t)row * D2 + oc] = v;
                }
            }
        }
    }
}

// ---------------- launch ----------------

extern "C" void kernel_launch(void* const* d_in, const int* in_sizes, int n_in,
                              void* d_out, int out_size, void* d_ws, size_t ws_size,
                              hipStream_t stream) {
    const float* x   = (const float*)d_in[0];
    const int*   ei  = (const int*)d_in[1];
    const float* W1l = (const float*)d_in[2];
    const float* W1r = (const float*)d_in[3];
    const float* b1  = (const float*)d_in[4];
    const float* W2l = (const float*)d_in[5];
    const float* W2r = (const float*)d_in[6];
    const float* b2  = (const float*)d_in[7];
    float* out = (float*)d_out;

    const int N = N_NODES;
    const int E = in_sizes[1] / 2;
    const int* src = ei;
    const int* dst = ei + E;

    char* p = (char*)d_ws;
    auto alloc = [&](size_t bytes) -> void* {
        void* r = (void*)p;
        p += (bytes + 255) & ~(size_t)255;
        return r;
    };
    const int nCount = (E + 2047) / 2048;          // 391
    const int nCast  = (N * D0) / 1024;            // 3125 (exact)

    int*      rowptr  = (int*)alloc((size_t)(N + 1) * 4);
    int*      csr     = (int*)alloc((size_t)E * 4);
    unsigned* ebuf    = (unsigned*)alloc((size_t)E * 4);
    int*      hist    = (int*)alloc((size_t)nCount * NB * 4);
    int*      bbase   = (int*)alloc(NB * 4);
    int*      bcursor = (int*)alloc(NB * 4);
    unsigned short* xh    = (unsigned short*)alloc((size_t)N * D0 * 2);
    unsigned short* aggh  = (unsigned short*)alloc((size_t)N * D0 * 2);
    unsigned short* wpk1  = (unsigned short*)alloc((size_t)32 * 64 * 8 * 2);
    unsigned short* wpk2  = (unsigned short*)alloc((size_t)20 * 64 * 8 * 2);
    unsigned short* p2h   = (unsigned short*)alloc((size_t)N * 64 * 2);   // 128 B stride
    float* r2buf = (float*)alloc((size_t)N * D2 * 4);

    // prep (hist + cast + pack) -> scan -> scatter -> fill
    prep_kernel<<<nCount + nCast + 8 + 5, 256, 0, stream>>>(
        x, dst, W1l, W1r, W2l, W2r, xh, hist, wpk1, wpk2, E, nCount, nCast);
    bucket_scan_kernel<<<1, NB, 0, stream>>>(hist, nCount, bbase, bcursor);
    bucket_scatter_kernel<<<(E + 4095) / 4096, 256, 0, stream>>>(src, dst, bcursor, ebuf, E);
    bucket_fill_kernel<<<NB, 256, 0, stream>>>(ebuf, bbase, rowptr, csr, E, N);

    // layer 1 aggregate, then fused GEMM1+ReLU+GEMM2 (hbuf eliminated)
    agg1_kernel<<<(N * 64 + 255) / 256, 256, 0, stream>>>(xh, rowptr, csr, aggh, N);
    gemm_fused<<<(N + 127) / 128, 256, 0, stream>>>(xh, aggh, wpk1, wpk2, b1, b2,
                                                    p2h, r2buf, N);

    // layer 2 aggregate of projected features + fused log_softmax
    agg2_kernel<<<(N * 64 + 255) / 256, 256, 0, stream>>>(p2h, r2buf, rowptr, csr,
                                                          out, out + (size_t)N * D2, N);
}

// Round 2
// 171.365 us; speedup vs baseline: 1.1738x; 1.1625x over previous
//
#include <hip/hip_runtime.h>
#include <hip/hip_bf16.h>
#include <math.h>

#define N_NODES 50000
#define N_EDGES 800000
#define D0 64
#define D1 128
#define D2 40

#define NB  512   // buckets
#define NPB 98    // nodes per bucket (512*98 = 50176 >= 50000)
#define CAP 2048  // per-bucket edge capacity (mean 1562, ~12 sigma headroom)

typedef short s16x8 __attribute__((ext_vector_type(8)));
typedef float f32x4 __attribute__((ext_vector_type(4)));

static __device__ __forceinline__ unsigned short f2bf(float v) {
    __hip_bfloat16 hb = __float2bfloat16(v);
    return *(unsigned short*)&hb;
}

// ---------------- fused prep: edge scatter to fixed-cap buckets + cast x + pack weights ----
__global__ __launch_bounds__(256) void prep_scatter_kernel(
        const float* __restrict__ x, const int* __restrict__ src, const int* __restrict__ dst,
        const float* __restrict__ W1l, const float* __restrict__ W1r,
        const float* __restrict__ W2l, const float* __restrict__ W2r,
        unsigned short* __restrict__ xh, int* __restrict__ gcur, unsigned* __restrict__ ebuf,
        unsigned short* __restrict__ wpk1, unsigned short* __restrict__ wpk2,
        int E, int nScat, int nCast) {
    int b = blockIdx.x, t = threadIdx.x;
    if (b < nScat) {
        __shared__ int h[NB];
        __shared__ int base[NB];
        int e0 = b * 4096;
        h[t] = 0; h[t + 256] = 0;
        __syncthreads();
        for (int i = t; i < 4096; i += 256) {
            int e = e0 + i;
            if (e < E) atomicAdd(&h[(unsigned)dst[e] / NPB], 1);
        }
        __syncthreads();
        for (int u = t; u < NB; u += 256)
            if (h[u] > 0) base[u] = u * CAP + atomicAdd(&gcur[u], h[u]);
        __syncthreads();
        h[t] = 0; h[t + 256] = 0;
        __syncthreads();
        for (int i = t; i < 4096; i += 256) {
            int e = e0 + i;
            if (e < E) {
                unsigned d = (unsigned)dst[e];
                unsigned bk = d / NPB;
                unsigned ld = d - bk * NPB;
                int k = atomicAdd(&h[bk], 1);
                ebuf[base[bk] + k] = (ld << 17) | (unsigned)src[e];
            }
        }
    } else if (b < nScat + nCast) {
        int i = ((b - nScat) * 256 + t) * 4;   // nCast*1024 == N*D0 exactly
        float4 v = *(const float4*)(x + i);
        unsigned o0 = (unsigned)f2bf(v.x) | ((unsigned)f2bf(v.y) << 16);
        unsigned o1 = (unsigned)f2bf(v.z) | ((unsigned)f2bf(v.w) << 16);
        uint2 pk; pk.x = o0; pk.y = o1;
        *(uint2*)(xh + i) = pk;
    } else if (b < nScat + nCast + 8) {
        int f = (b - nScat - nCast) * 4 + (t >> 6);   // 0..31
        int lane = t & 63;
        int nt = f & 7;
        int col = nt * 16 + (lane & 15);
        int kbase = (f >> 3) * 32 + (lane >> 4) * 8;
        unsigned short* o = wpk1 + ((size_t)f * 64 + lane) * 8;
#pragma unroll
        for (int j = 0; j < 8; ++j) {
            int k = kbase + j;
            float w = (k < 64) ? W1r[k * 128 + col] : W1l[(k - 64) * 128 + col];
            o[j] = f2bf(w);
        }
    } else {
        int f = (b - nScat - nCast - 8) * 4 + (t >> 6);   // 0..19
        if (f < 20) {
            int lane = t & 63;
            int nt = f % 5;
            int col = nt * 16 + (lane & 15);       // 0..79
            int kbase = (f / 5) * 32 + (lane >> 4) * 8;
            unsigned short* o = wpk2 + ((size_t)f * 64 + lane) * 8;
#pragma unroll
            for (int j = 0; j < 8; ++j) {
                int k = kbase + j;
                float w = (col < 40) ? W2l[k * 40 + col] : W2r[k * 40 + (col - 40)];
                o[j] = f2bf(w);
            }
        }
    }
}

// ---------------- fill: per-bucket local CSR (rowstart/rowcnt into padded csr) ----------------
__global__ __launch_bounds__(256) void bucket_fill_kernel(
        const unsigned* __restrict__ ebuf, const int* __restrict__ gcur,
        int* __restrict__ rowstart, int* __restrict__ rowcnt,
        int* __restrict__ csr, int N) {
    __shared__ int cnt[128];
    __shared__ int sd[128];
    int b = blockIdx.x, t = threadIdx.x;
    int s0 = b * CAP;
    int s1 = s0 + gcur[b];
    int lo = b * NPB;
    if (t < 128) cnt[t] = 0;
    __syncthreads();
    for (int i = s0 + t; i < s1; i += 256)
        atomicAdd(&cnt[ebuf[i] >> 17], 1);
    __syncthreads();
    int v = 0;
    if (t < 128) { v = cnt[t]; sd[t] = v; }
    __syncthreads();
    for (int off = 1; off < 128; off <<= 1) {
        int u = (t >= off && t < 128) ? sd[t - off] : 0;
        __syncthreads();
        if (t < 128) sd[t] += u;
        __syncthreads();
    }
    int node = lo + t;
    if (t < NPB && node < N) {
        rowstart[node] = s0 + sd[t] - v;
        rowcnt[node] = v;
    }
    if (t < 128) cnt[t] = s0 + sd[t] - v;
    __syncthreads();
    for (int i = s0 + t; i < s1; i += 256) {
        unsigned pk = ebuf[i];
        int p = atomicAdd(&cnt[pk >> 17], 1);
        csr[p] = (int)(pk & 0x1FFFFu);
    }
}

// ---------------- agg1: 8 lanes/edge, 8 edges/load-instr, 8-slot padding ----------------

__global__ void agg1_kernel(const unsigned short* __restrict__ xh, const int* __restrict__ rowstart,
                            const int* __restrict__ rowcnt,
                            const int* __restrict__ csr, unsigned short* __restrict__ aggh, int N) {
    int wid = (blockIdx.x * blockDim.x + threadIdx.x) >> 6;
    int lane = threadIdx.x & 63;
    if (wid >= N) return;
    int beg = rowstart[wid];
    int deg = rowcnt[wid];
    int l = lane & 7, g = lane >> 3;
    float acc[8];
#pragma unroll
    for (int k = 0; k < 8; ++k) acc[k] = 0.f;
    int jmax = (deg + 7) >> 3;          // # of 8-slot blocks
    int full = jmax - 1;                // blocks [0,full) are provably full: no clamp, no mask
    int j = 0;
    for (; j + 2 <= full; j += 2) {
        int s0 = csr[beg + j * 8 + g];
        int s1 = csr[beg + (j + 1) * 8 + g];
        uint4 v0 = *(const uint4*)(xh + (size_t)s0 * D0 + l * 8);
        uint4 v1 = *(const uint4*)(xh + (size_t)s1 * D0 + l * 8);
        acc[0] += __uint_as_float(v0.x << 16);          acc[1] += __uint_as_float(v0.x & 0xffff0000u);
        acc[2] += __uint_as_float(v0.y << 16);          acc[3] += __uint_as_float(v0.y & 0xffff0000u);
        acc[4] += __uint_as_float(v0.z << 16);          acc[5] += __uint_as_float(v0.z & 0xffff0000u);
        acc[6] += __uint_as_float(v0.w << 16);          acc[7] += __uint_as_float(v0.w & 0xffff0000u);
        acc[0] += __uint_as_float(v1.x << 16);          acc[1] += __uint_as_float(v1.x & 0xffff0000u);
        acc[2] += __uint_as_float(v1.y << 16);          acc[3] += __uint_as_float(v1.y & 0xffff0000u);
        acc[4] += __uint_as_float(v1.z << 16);          acc[5] += __uint_as_float(v1.z & 0xffff0000u);
        acc[6] += __uint_as_float(v1.w << 16);          acc[7] += __uint_as_float(v1.w & 0xffff0000u);
    }
    if (j < full) {
        int s0 = csr[beg + j * 8 + g];
        uint4 v0 = *(const uint4*)(xh + (size_t)s0 * D0 + l * 8);
        acc[0] += __uint_as_float(v0.x << 16);          acc[1] += __uint_as_float(v0.x & 0xffff0000u);
        acc[2] += __uint_as_float(v0.y << 16);          acc[3] += __uint_as_float(v0.y & 0xffff0000u);
        acc[4] += __uint_as_float(v0.z << 16);          acc[5] += __uint_as_float(v0.z & 0xffff0000u);
        acc[6] += __uint_as_float(v0.w << 16);          acc[7] += __uint_as_float(v0.w & 0xffff0000u);
    }
    if (jmax > 0) {                     // last (possibly partial) block, masked
        int slot = full * 8 + g;
        int e = beg + ((slot < deg) ? slot : (deg - 1));
        int s0 = csr[e];
        float w = (slot < deg) ? 1.f : 0.f;
        uint4 v0 = *(const uint4*)(xh + (size_t)s0 * D0 + l * 8);
        acc[0] = fmaf(w, __uint_as_float(v0.x << 16), acc[0]);
        acc[1] = fmaf(w, __uint_as_float(v0.x & 0xffff0000u), acc[1]);
        acc[2] = fmaf(w, __uint_as_float(v0.y << 16), acc[2]);
        acc[3] = fmaf(w, __uint_as_float(v0.y & 0xffff0000u), acc[3]);
        acc[4] = fmaf(w, __uint_as_float(v0.z << 16), acc[4]);
        acc[5] = fmaf(w, __uint_as_float(v0.z & 0xffff0000u), acc[5]);
        acc[6] = fmaf(w, __uint_as_float(v0.w << 16), acc[6]);
        acc[7] = fmaf(w, __uint_as_float(v0.w & 0xffff0000u), acc[7]);
    }
#pragma unroll
    for (int off = 8; off <= 32; off <<= 1) {
#pragma unroll
        for (int k = 0; k < 8; ++k) acc[k] += __shfl_xor(acc[k], off);
    }
    float inv = 1.f / (float)max(deg, 1);
    if (g == 0) {
        unsigned o0 = (unsigned)f2bf(acc[0] * inv) | ((unsigned)f2bf(acc[1] * inv) << 16);
        unsigned o1 = (unsigned)f2bf(acc[2] * inv) | ((unsigned)f2bf(acc[3] * inv) << 16);
        unsigned o2 = (unsigned)f2bf(acc[4] * inv) | ((unsigned)f2bf(acc[5] * inv) << 16);
        unsigned o3 = (unsigned)f2bf(acc[6] * inv) | ((unsigned)f2bf(acc[7] * inv) << 16);
        uint4 pk; pk.x = o0; pk.y = o1; pk.z = o2; pk.w = o3;
        *(uint4*)(aggh + (size_t)wid * D0 + l * 8) = pk;
    }
}

// ---------------- agg2 + log_softmax: 5 lanes/edge x uint4, 12 edges/instr ----------------
// p2h rows padded to 64 shorts (128 B) -> every edge gather = exactly one cache line

__global__ void agg2_kernel(const unsigned short* __restrict__ p2h, const float* __restrict__ r2,
                            const int* __restrict__ rowstart, const int* __restrict__ rowcnt,
                            const int* __restrict__ csr,
                            float* __restrict__ out, float* __restrict__ out2, int N) {
    int wid = (blockIdx.x * blockDim.x + threadIdx.x) >> 6;
    int lane = threadIdx.x & 63;
    if (wid >= N) return;
    int beg = rowstart[wid];
    int deg = rowcnt[wid];
    int g = lane / 5;             // 0..12 (g==12: lanes 60..63 idle)
    int l = lane - g * 5;         // 0..4
    bool gv = g < 12;
    float a[8];
#pragma unroll
    for (int k = 0; k < 8; ++k) a[k] = 0.f;
    int jmax = (deg + 11) / 12;   // # of 12-slot blocks
    int full = jmax - 1;          // blocks [0,full): every slot < deg even for g==11
    int j = 0;
    for (; j + 2 <= full; j += 2) {
        int s0 = csr[beg + j * 12 + g];
        int s1 = csr[beg + (j + 1) * 12 + g];
        uint4 v0 = *(const uint4*)(p2h + (size_t)s0 * 64 + l * 8);
        uint4 v1 = *(const uint4*)(p2h + (size_t)s1 * 64 + l * 8);
        if (gv) {
            a[0] += __uint_as_float(v0.x << 16);  a[1] += __uint_as_float(v0.x & 0xffff0000u);
            a[2] += __uint_as_float(v0.y << 16);  a[3] += __uint_as_float(v0.y & 0xffff0000u);
            a[4] += __uint_as_float(v0.z << 16);  a[5] += __uint_as_float(v0.z & 0xffff0000u);
            a[6] += __uint_as_float(v0.w << 16);  a[7] += __uint_as_float(v0.w & 0xffff0000u);
            a[0] += __uint_as_float(v1.x << 16);  a[1] += __uint_as_float(v1.x & 0xffff0000u);
            a[2] += __uint_as_float(v1.y << 16);  a[3] += __uint_as_float(v1.y & 0xffff0000u);
            a[4] += __uint_as_float(v1.z << 16);  a[5] += __uint_as_float(v1.z & 0xffff0000u);
            a[6] += __uint_as_float(v1.w << 16);  a[7] += __uint_as_float(v1.w & 0xffff0000u);
        }
    }
    if (j < full) {
        int s0 = csr[beg + j * 12 + g];
        uint4 v0 = *(const uint4*)(p2h + (size_t)s0 * 64 + l * 8);
        if (gv) {
            a[0] += __uint_as_float(v0.x << 16);  a[1] += __uint_as_float(v0.x & 0xffff0000u);
            a[2] += __uint_as_float(v0.y << 16);  a[3] += __uint_as_float(v0.y & 0xffff0000u);
            a[4] += __uint_as_float(v0.z << 16);  a[5] += __uint_as_float(v0.z & 0xffff0000u);
            a[6] += __uint_as_float(v0.w << 16);  a[7] += __uint_as_float(v0.w & 0xffff0000u);
        }
    }
    if (jmax > 0) {               // last block, masked + clamped
        int slot = full * 12 + g;
        int e = beg + ((slot < deg) ? slot : (deg - 1));
        int s0 = csr[e];
        float w = (gv && slot < deg) ? 1.f : 0.f;
        uint4 v0 = *(const uint4*)(p2h + (size_t)s0 * 64 + l * 8);
        a[0] = fmaf(w, __uint_as_float(v0.x << 16), a[0]);
        a[1] = fmaf(w, __uint_as_float(v0.x & 0xffff0000u), a[1]);
        a[2] = fmaf(w, __uint_as_float(v0.y << 16), a[2]);
        a[3] = fmaf(w, __uint_as_float(v0.y & 0xffff0000u), a[3]);
        a[4] = fmaf(w, __uint_as_float(v0.z << 16), a[4]);
        a[5] = fmaf(w, __uint_as_float(v0.z & 0xffff0000u), a[5]);
        a[6] = fmaf(w, __uint_as_float(v0.w << 16), a[6]);
        a[7] = fmaf(w, __uint_as_float(v0.w & 0xffff0000u), a[7]);
    }
    // reduce 12 groups -> group 0 (lanes 0..4, 8 dims each)
    {
        float b0;
#pragma unroll
        for (int k = 0; k < 8; ++k) { b0 = __shfl(a[k], lane + 30); if (g < 6) a[k] += b0; }
#pragma unroll
        for (int k = 0; k < 8; ++k) { b0 = __shfl(a[k], lane + 15); if (g < 3) a[k] += b0; }
#pragma unroll
        for (int k = 0; k < 8; ++k) {
            float b1 = __shfl(a[k], lane + 5);
            float b2 = __shfl(a[k], lane + 10);
            if (g == 0) a[k] += b1 + b2;
        }
    }
    float inv = 1.f / (float)max(deg, 1);
    bool wr = (lane < 5);
    float h2[8];
    if (wr) {
        float4 ra = *(const float4*)(r2 + (size_t)wid * D2 + lane * 8);
        float4 rb = *(const float4*)(r2 + (size_t)wid * D2 + lane * 8 + 4);
        h2[0] = ra.x + a[0] * inv; h2[1] = ra.y + a[1] * inv;
        h2[2] = ra.z + a[2] * inv; h2[3] = ra.w + a[3] * inv;
        h2[4] = rb.x + a[4] * inv; h2[5] = rb.y + a[5] * inv;
        h2[6] = rb.z + a[6] * inv; h2[7] = rb.w + a[7] * inv;
        float4 oa; oa.x = h2[0]; oa.y = h2[1]; oa.z = h2[2]; oa.w = h2[3];
        float4 ob; ob.x = h2[4]; ob.y = h2[5]; ob.z = h2[6]; ob.w = h2[7];
        *(float4*)(out + (size_t)wid * D2 + lane * 8) = oa;
        *(float4*)(out + (size_t)wid * D2 + lane * 8 + 4) = ob;
    }
    float m = -INFINITY;
    if (wr) {
#pragma unroll
        for (int k = 0; k < 8; ++k) m = fmaxf(m, h2[k]);
    }
#pragma unroll
    for (int off = 1; off < 64; off <<= 1) m = fmaxf(m, __shfl_xor(m, off));
    float s = 0.f;
    if (wr) {
#pragma unroll
        for (int k = 0; k < 8; ++k) s += expf(h2[k] - m);
    }
#pragma unroll
    for (int off = 1; off < 64; off <<= 1) s += __shfl_xor(s, off);
    if (wr) {
        float lg = m + logf(s);
        float4 oa; oa.x = h2[0] - lg; oa.y = h2[1] - lg; oa.z = h2[2] - lg; oa.w = h2[3] - lg;
        float4 ob; ob.x = h2[4] - lg; ob.y = h2[5] - lg; ob.z = h2[6] - lg; ob.w = h2[7] - lg;
        *(float4*)(out2 + (size_t)wid * D2 + lane * 8) = oa;
        *(float4*)(out2 + (size_t)wid * D2 + lane * 8 + 4) = ob;
    }
}

// ---------------- fused GEMM: h=relu([x|agg]@[W1r;W1l]+b1) staged in LDS, then
//                  p2h(bf16,stride64)=h@W2l ; r2(f32)=h@W2r+b2 ----------------
__global__ __launch_bounds__(256) void gemm_fused(
        const unsigned short* __restrict__ xh, const unsigned short* __restrict__ aggh,
        const unsigned short* __restrict__ Wpk1, const unsigned short* __restrict__ Wpk2,
        const float* __restrict__ b1, const float* __restrict__ b2,
        unsigned short* __restrict__ p2h, float* __restrict__ r2, int N) {
    __shared__ __align__(16) unsigned short As[128 * 136];  // [row][k], +8 pad
    int t = threadIdx.x;
    int r0 = blockIdx.x * 128;
    for (int i = t; i < 2048; i += 256) {
        int r = i >> 4, c = i & 15;
        int gr = r0 + r; gr = (gr < N) ? gr : (N - 1);
        uint4 v = (c < 8) ? ((const uint4*)(xh + (size_t)gr * 64))[c]
                          : ((const uint4*)(aggh + (size_t)gr * 64))[c - 8];
        *(uint4*)(As + r * 136 + c * 8) = v;
    }
    __syncthreads();
    int w = t >> 6, lane = t & 63;
    int l15 = lane & 15, q = lane >> 4;
    f32x4 zero = {0.f, 0.f, 0.f, 0.f};
    const unsigned short* abase = As + (w * 32 + l15) * 136 + q * 8;

    // ---- phase 1: [x|agg] @ [W1r;W1l] ----
    f32x4 acc[2][8];
#pragma unroll
    for (int rt = 0; rt < 2; ++rt)
#pragma unroll
        for (int nt = 0; nt < 8; ++nt) acc[rt][nt] = zero;
#pragma unroll
    for (int ks = 0; ks < 4; ++ks) {
        s16x8 a0 = *(const s16x8*)(abase + ks * 32);
        s16x8 a1 = *(const s16x8*)(abase + 16 * 136 + ks * 32);
        s16x8 b[8];
#pragma unroll
        for (int nt = 0; nt < 8; ++nt)
            b[nt] = *(const s16x8*)(Wpk1 + ((size_t)(ks * 8 + nt) * 64 + lane) * 8);
#pragma unroll
        for (int nt = 0; nt < 8; ++nt) {
            acc[0][nt] = __builtin_amdgcn_mfma_f32_16x16x32_bf16(a0, b[nt], acc[0][nt], 0, 0, 0);
            acc[1][nt] = __builtin_amdgcn_mfma_f32_16x16x32_bf16(a1, b[nt], acc[1][nt], 0, 0, 0);
        }
    }
    __syncthreads();   // all reads of As complete before overwrite
    // ---- stage h = relu(acc + b1) back into As (each wave owns rows [w*32, w*32+32)) ----
    int rloc = w * 32 + q * 4;
#pragma unroll
    for (int nt = 0; nt < 8; ++nt) {
        int col = nt * 16 + l15;
        float bias = b1[col];
#pragma unroll
        for (int rt = 0; rt < 2; ++rt) {
#pragma unroll
            for (int reg = 0; reg < 4; ++reg) {
                int row = rloc + rt * 16 + reg;
                As[row * 136 + col] = f2bf(fmaxf(acc[rt][nt][reg] + bias, 0.f));
            }
        }
    }
    __syncthreads();
    // ---- phase 2: h @ [W2l|W2r] ----
    f32x4 acc2[2][5];
#pragma unroll
    for (int rt = 0; rt < 2; ++rt)
#pragma unroll
        for (int nt = 0; nt < 5; ++nt) acc2[rt][nt] = zero;
#pragma unroll
    for (int ks = 0; ks < 4; ++ks) {
        s16x8 a0 = *(const s16x8*)(abase + ks * 32);
        s16x8 a1 = *(const s16x8*)(abase + 16 * 136 + ks * 32);
        s16x8 b[5];
#pragma unroll
        for (int nt = 0; nt < 5; ++nt)
            b[nt] = *(const s16x8*)(Wpk2 + ((size_t)(ks * 5 + nt) * 64 + lane) * 8);
#pragma unroll
        for (int nt = 0; nt < 5; ++nt) {
            acc2[0][nt] = __builtin_amdgcn_mfma_f32_16x16x32_bf16(a0, b[nt], acc2[0][nt], 0, 0, 0);
            acc2[1][nt] = __builtin_amdgcn_mfma_f32_16x16x32_bf16(a1, b[nt], acc2[1][nt], 0, 0, 0);
        }
    }
    int rbase = r0 + w * 32 + q * 4;
#pragma unroll
    for (int nt = 0; nt < 5; ++nt) {
        int col = nt * 16 + l15;   // 0..79
        bool isp = col < 40;
        int oc = isp ? col : (col - 40);
        float bias = isp ? 0.f : b2[oc];
#pragma unroll
        for (int rt = 0; rt < 2; ++rt) {
#pragma unroll
            for (int reg = 0; reg < 4; ++reg) {
                int row = rbase + rt * 16 + reg;
                if (row < N) {
                    float v = acc2[rt][nt][reg] + bias;
                    if (isp) p2h[(size_t)row * 64 + oc] = f2bf(v);
                    else     r2[(size_t)row * D2 + oc] = v;
                }
            }
        }
    }
}

// ---------------- launch ----------------

extern "C" void kernel_launch(void* const* d_in, const int* in_sizes, int n_in,
                              void* d_out, int out_size, void* d_ws, size_t ws_size,
                              hipStream_t stream) {
    const float* x   = (const float*)d_in[0];
    const int*   ei  = (const int*)d_in[1];
    const float* W1l = (const float*)d_in[2];
    const float* W1r = (const float*)d_in[3];
    const float* b1  = (const float*)d_in[4];
    const float* W2l = (const float*)d_in[5];
    const float* W2r = (const float*)d_in[6];
    const float* b2  = (const float*)d_in[7];
    float* out = (float*)d_out;

    const int N = N_NODES;
    const int E = in_sizes[1] / 2;
    const int* src = ei;
    const int* dst = ei + E;

    char* p = (char*)d_ws;
    auto alloc = [&](size_t bytes) -> void* {
        void* r = (void*)p;
        p += (bytes + 255) & ~(size_t)255;
        return r;
    };
    const int nScat = (E + 4095) / 4096;           // 196
    const int nCast = (N * D0) / 1024;             // 3125 (exact)

    int*      rowstart = (int*)alloc((size_t)N * 4);
    int*      rowcnt   = (int*)alloc((size_t)N * 4);
    int*      csr      = (int*)alloc((size_t)NB * CAP * 4);   // 4 MB, bucket-padded
    unsigned* ebuf     = (unsigned*)alloc((size_t)NB * CAP * 4);
    int*      gcur     = (int*)alloc(NB * 4);
    unsigned short* xh    = (unsigned short*)alloc((size_t)N * D0 * 2);
    unsigned short* aggh  = (unsigned short*)alloc((size_t)N * D0 * 2);
    unsigned short* wpk1  = (unsigned short*)alloc((size_t)32 * 64 * 8 * 2);
    unsigned short* wpk2  = (unsigned short*)alloc((size_t)20 * 64 * 8 * 2);
    unsigned short* p2h   = (unsigned short*)alloc((size_t)N * 64 * 2);   // 128 B stride
    float* r2buf = (float*)alloc((size_t)N * D2 * 4);

    // zero bucket cursors (2 KB), then fused prep (scatter + cast + pack), then fill
    hipMemsetAsync(gcur, 0, NB * sizeof(int), stream);
    prep_scatter_kernel<<<nScat + nCast + 8 + 5, 256, 0, stream>>>(
        x, src, dst, W1l, W1r, W2l, W2r, xh, gcur, ebuf, wpk1, wpk2, E, nScat, nCast);
    bucket_fill_kernel<<<NB, 256, 0, stream>>>(ebuf, gcur, rowstart, rowcnt, csr, N);

    // layer 1 aggregate, then fused GEMM1+ReLU+GEMM2
    agg1_kernel<<<(N * 64 + 255) / 256, 256, 0, stream>>>(xh, rowstart, rowcnt, csr, aggh, N);
    gemm_fused<<<(N + 127) / 128, 256, 0, stream>>>(xh, aggh, wpk1, wpk2, b1, b2,
                                                    p2h, r2buf, N);

    // layer 2 aggregate of projected features + fused log_softmax
    agg2_kernel<<<(N * 64 + 255) / 256, 256, 0, stream>>>(p2h, r2buf, rowstart, rowcnt, csr,
                                                          out, out + (size_t)N * D2, N);
}